// Round 17
// baseline (54.280 us; speedup 1.0000x reference)
//
#include <hip/hip_runtime.h>
#include <stdint.h>

#define BATCH 16
#define NPTS 4096
#define DIM 384
#define NTOK (2*NPTS)
#define F4PT (DIM/4)   // 96 float4 groups per token
#define NRUN 16        // sorted runs per (b,v)
#define RUN 256        // elements per run

typedef unsigned long long u64;

// Morton spread: place bit b of an 8-bit value at position 3b.
__device__ __forceinline__ uint32_t spread3(uint32_t x) {
    x = (x | (x << 8)) & 0x00F00Fu;
    x = (x | (x << 4)) & 0x0C30C3u;
    x = (x | (x << 2)) & 0x249249u;
    return x;
}

// Exact port of the reference Skilling transform (bits=8, ndim=3).
__device__ __forceinline__ uint32_t hilbert3(uint32_t x0, uint32_t x1, uint32_t x2) {
    #pragma unroll
    for (uint32_t q = 128; q > 1; q >>= 1) {
        uint32_t pm = q - 1;
        if (x0 & q) x0 ^= pm;
        uint32_t t = (x0 ^ x1) & pm;
        if (x1 & q) { x0 ^= pm; } else { x0 ^= t; x1 ^= t; }
        t = (x0 ^ x2) & pm;
        if (x2 & q) { x0 ^= pm; } else { x0 ^= t; x2 ^= t; }
    }
    x1 ^= x0;
    x2 ^= x1;
    uint32_t t = 0;
    #pragma unroll
    for (uint32_t q = 128; q > 1; q >>= 1) { if (x2 & q) t ^= (q - 1); }
    x0 ^= t; x1 ^= t; x2 ^= t;
    return (spread3(x0) << 2) | (spread3(x1) << 1) | spread3(x2);
}

// K1: block = (b, v, sed), sed in [0,16). 256 threads, 1 element each.
// Batch minmax (48 KB, L2-hot, redundant per block - cheap), code own point,
// 3-pass 8-bit STABLE radix sort of the 256-element run by code (idx is pure
// payload), write split u32 code / u16 idx arrays. 512 blocks -> 2 blocks/CU
// co-resident: LDS-chain/barrier latency of one block hides under the other.
__global__ __launch_bounds__(256) void order_radix_s(const float* __restrict__ x,
                                                     uint32_t* __restrict__ segc_all,
                                                     unsigned short* __restrict__ segi_all) {
    const int bi = blockIdx.x;
    const int b = bi >> 5;
    const int v = (bi >> 4) & 1;
    const int sed = bi & 15;
    const int t = threadIdx.x;
    const int lane = t & 63;
    const int w = t >> 6;          // 4 waves

    __shared__ uint32_t scode[RUN];          // 1 KB
    __shared__ unsigned short slocal[RUN];   // 0.5 KB
    __shared__ uint32_t hist[3 * 1024];      // per-pass hist[p][d*4+w], 12 KB
    __shared__ uint32_t baseArr[256];        // 1 KB
    __shared__ uint32_t waveTot[4];
    __shared__ float red[4 * 6];

    const float* xb = x + (size_t)b * NPTS * 3;
    const float4* xb4 = (const float4*)xb;

    // --- vectorized batch min/max: 16 points/thread ---
    float mnx = 1e30f, mny = 1e30f, mnz = 1e30f;
    float mxx = -1e30f, mxy = -1e30f, mxz = -1e30f;
    #pragma unroll
    for (int g = 0; g < 4; ++g) {
        float4 q0 = xb4[12*t + 3*g + 0];
        float4 q1 = xb4[12*t + 3*g + 1];
        float4 q2 = xb4[12*t + 3*g + 2];
        float px[4] = {q0.x, q0.w, q1.z, q2.y};
        float py[4] = {q0.y, q1.x, q1.w, q2.z};
        float pz[4] = {q0.z, q1.y, q2.x, q2.w};
        #pragma unroll
        for (int r = 0; r < 4; ++r) {
            mnx = fminf(mnx, px[r]); mxx = fmaxf(mxx, px[r]);
            mny = fminf(mny, py[r]); mxy = fmaxf(mxy, py[r]);
            mnz = fminf(mnz, pz[r]); mxz = fmaxf(mxz, pz[r]);
        }
    }
    #pragma unroll
    for (int off = 32; off > 0; off >>= 1) {
        mnx = fminf(mnx, __shfl_xor(mnx, off));
        mny = fminf(mny, __shfl_xor(mny, off));
        mnz = fminf(mnz, __shfl_xor(mnz, off));
        mxx = fmaxf(mxx, __shfl_xor(mxx, off));
        mxy = fmaxf(mxy, __shfl_xor(mxy, off));
        mxz = fmaxf(mxz, __shfl_xor(mxz, off));
    }
    if (lane == 0) {
        red[w*6+0] = mnx; red[w*6+1] = mny; red[w*6+2] = mnz;
        red[w*6+3] = mxx; red[w*6+4] = mxy; red[w*6+5] = mxz;
    }
    // Zero all per-pass hist regions while the reduction settles.
    #pragma unroll
    for (int c = 0; c < 12; ++c) hist[t + c * 256] = 0u;
    __syncthreads();
    if (t == 0) {
        for (int ww = 1; ww < 4; ++ww) {
            mnx = fminf(mnx, red[ww*6+0]); mny = fminf(mny, red[ww*6+1]);
            mnz = fminf(mnz, red[ww*6+2]); mxx = fmaxf(mxx, red[ww*6+3]);
            mxy = fmaxf(mxy, red[ww*6+4]); mxz = fmaxf(mxz, red[ww*6+5]);
        }
        red[0] = mnx; red[1] = mny; red[2] = mnz;
        red[3] = fmaxf(mxx - mnx, 1e-6f);
        red[4] = fmaxf(mxy - mny, 1e-6f);
        red[5] = fmaxf(mxz - mnz, 1e-6f);
    }
    __syncthreads();
    mnx = red[0]; mny = red[1]; mnz = red[2];
    const float spx = red[3], spy = red[4], spz = red[5];

    // Code own point n0 = sed*256 + t.
    uint32_t code;
    unsigned short myidx;
    {
        const int n0 = (sed << 8) + t;
        float cx = xb[3*n0+0], cy = xb[3*n0+1], cz = xb[3*n0+2];
        float gx = fminf(fmaxf(((cx - mnx) / spx) * 255.0f, 0.0f), 255.0f);
        float gy = fminf(fmaxf(((cy - mny) / spy) * 255.0f, 0.0f), 255.0f);
        float gz = fminf(fmaxf(((cz - mnz) / spz) * 255.0f, 0.0f), 255.0f);
        uint32_t ix = (uint32_t)(int)gx;
        uint32_t iy = (uint32_t)(int)gy;
        uint32_t iz = (uint32_t)(int)gz;
        uint32_t a0 = v ? iz : ix;
        uint32_t a2 = v ? ix : iz;
        code = hilbert3(a0, iy, a2);
        myidx = (unsigned short)n0;
    }

    const u64 below_mask = (1ull << lane) - 1ull;
    uint32_t* segc = segc_all + (((b << 1) | v) << 12);
    unsigned short* segi = segi_all + (((b << 1) | v) << 12);

    // 3 stable radix passes, 8-bit digits over code bits [0, 24).
    #pragma unroll
    for (int p = 0; p < 3; ++p) {
        const int sh = 8 * p;
        uint32_t* histp = hist + p * 1024;

        unsigned d = (code >> sh) & 255u;
        u64 m = ~0ull;
        #pragma unroll
        for (int bit = 0; bit < 8; ++bit) {
            u64 bal = __ballot((int)((d >> bit) & 1u));
            m &= ((d >> bit) & 1u) ? bal : ~bal;
        }
        unsigned rk = (unsigned)__popcll(m & below_mask);
        if (rk == 0u)
            histp[d * 4 + w] = (unsigned)__popcll(m);
        __syncthreads();   // B1

        // All 256 threads: serial-scan own bin's 4 slots; 64-lane shfl scan
        // of bin totals; waveTot combine after barrier.
        unsigned exclw;
        {
            uint32_t* hb = histp + t * 4;
            unsigned running = 0;
            #pragma unroll
            for (int s = 0; s < 4; ++s) {
                unsigned hv = hb[s];
                hb[s] = running;
                running += hv;
            }
            unsigned incl = running;
            #pragma unroll
            for (int off = 1; off < 64; off <<= 1) {
                unsigned nv = __shfl_up(incl, off);
                if (lane >= off) incl += nv;
            }
            if (lane == 63) waveTot[w] = incl;
            exclw = incl - running;
        }
        __syncthreads();   // B1.5

        {
            unsigned base = exclw;
            #pragma unroll
            for (int ww = 0; ww < 4; ++ww)
                if (ww < w) base += waveTot[ww];
            baseArr[t] = base;
        }
        __syncthreads();   // B2

        unsigned pos = baseArr[d] + histp[d * 4 + w] + rk;

        if (p < 2) {
            scode[pos] = code;
            slocal[pos] = myidx;
            __syncthreads();   // B3
            code = scode[t];
            myidx = slocal[t];
        } else {
            segc[(sed << 8) + pos] = code;
            segi[(sed << 8) + pos] = myidx;
        }
    }
}

// K2: block = (b, v, oct), 512 threads. Early-loads own code/idx/coords,
// stages all 16 runs' CODES (16 KB, uint4), ranks each own element via 15
// interleaved 8-step binary searches with run-order tie-break (count in run
// j = #{c' < kc + (j < jown)} -- exact argsort rank since run idx-ranges are
// disjoint and ordered), then emits the 512 output rows.
__global__ __launch_bounds__(512) void merge_emit_kernel(const float* __restrict__ x,
                                                         const float* __restrict__ W,
                                                         const float* __restrict__ bias,
                                                         const float* __restrict__ gamma,
                                                         const float* __restrict__ beta,
                                                         const uint32_t* __restrict__ segc_all,
                                                         const unsigned short* __restrict__ segi_all,
                                                         float4* __restrict__ out4) {
    const int bi = blockIdx.x;
    const int b = bi >> 4;
    const int v = (bi >> 3) & 1;
    const int oct = bi & 7;
    const int t = threadIdx.x;

    __shared__ uint32_t runs[NRUN * RUN];               // 16 KB
    __shared__ __align__(16) float sw0[DIM], sw1[DIM], sw2[DIM], sc[DIM];  // 6 KB
    __shared__ float cxs[512], cys[512], czs[512];      // 6 KB
    __shared__ int rnk[512];                            // 2 KB

    const uint32_t* segc = segc_all + (((b << 1) | v) << 12);
    const unsigned short* segi = segi_all + (((b << 1) | v) << 12);

    // Early independent loads: own code, idx, coords (land under staging).
    const int flat = (oct << 9) + t;
    uint32_t kc = segc[flat];
    int idx = (int)segi[flat];
    const float* p = x + (size_t)b * NPTS * 3 + idx * 3;
    float pcx = p[0], pcy = p[1], pcz = p[2];

    // Coeffs (fused gamma/beta), one v per block.
    if (t < DIM) {
        float g = gamma[v * DIM + t];
        sw0[t] = g * W[t*3+0];
        sw1[t] = g * W[t*3+1];
        sw2[t] = g * W[t*3+2];
        sc[t]  = g * bias[t] + beta[v * DIM + t];
    }

    // Stage all 16 runs' codes as uint4 (2 x 16 B per thread).
    {
        const uint4* s4 = (const uint4*)segc;
        uint4* r4 = (uint4*)runs;
        r4[t] = s4[t];
        r4[t + 512] = s4[t + 512];
    }
    __syncthreads();

    // Rank = position in own run + counts in the other 15 runs.
    const int jown = flat >> 8;      // own run index
    int rank = flat & (RUN - 1);
    {
        int base15[15];
        uint32_t thr15[15];
        int c[15];
        #pragma unroll
        for (int j = 0; j < 15; ++j) {
            int oq = j + (j >= jown ? 1 : 0);
            base15[j] = oq << 8;
            thr15[j] = kc + (oq < jown ? 1u : 0u);
            c[j] = 0;
        }
        #pragma unroll
        for (int step = RUN; step >= 1; step >>= 1) {
            #pragma unroll
            for (int j = 0; j < 15; ++j) {
                if (c[j] + step <= RUN && runs[base15[j] + c[j] + step - 1] < thr15[j])
                    c[j] += step;
            }
        }
        #pragma unroll
        for (int j = 0; j < 15; ++j) rank += c[j];
    }

    cxs[t] = pcx; cys[t] = pcy; czs[t] = pcz;
    rnk[t] = rank;
    __syncthreads();

    // Emit 512 rows x 96 float4 groups; lane-contiguous within rows.
    const int tokbase = (b << 13) + (v << 12);
    for (int i = t; i < 512 * F4PT; i += 512) {
        int r = i / F4PT;
        int g = i - r * F4PT;
        float pxr = cxs[r], pyr = cys[r], pzr = czs[r];
        int d0 = g << 2;
        float4 w0 = *(const float4*)&sw0[d0];
        float4 w1 = *(const float4*)&sw1[d0];
        float4 w2 = *(const float4*)&sw2[d0];
        float4 cc = *(const float4*)&sc[d0];
        float4 o;
        o.x = pxr*w0.x + pyr*w1.x + pzr*w2.x + cc.x;
        o.y = pxr*w0.y + pyr*w1.y + pzr*w2.y + cc.y;
        o.z = pxr*w0.z + pyr*w1.z + pzr*w2.z + cc.z;
        o.w = pxr*w0.w + pyr*w1.w + pzr*w2.w + cc.w;
        out4[(size_t)(tokbase + rnk[r]) * F4PT + g] = o;
    }
}

extern "C" void kernel_launch(void* const* d_in, const int* in_sizes, int n_in,
                              void* d_out, int out_size, void* d_ws, size_t ws_size,
                              hipStream_t stream) {
    const float* x     = (const float*)d_in[0];
    const float* W     = (const float*)d_in[1];
    const float* bias  = (const float*)d_in[2];
    const float* gamma = (const float*)d_in[3];
    const float* beta  = (const float*)d_in[4];

    uint32_t* segc_all = (uint32_t*)d_ws;                       // 32*4096*4 = 512 KB
    unsigned short* segi_all = (unsigned short*)(segc_all + 32 * 4096);  // 256 KB

    hipLaunchKernelGGL(order_radix_s,     dim3(BATCH * 32), dim3(256), 0, stream,
                       x, segc_all, segi_all);
    hipLaunchKernelGGL(merge_emit_kernel, dim3(BATCH * 16), dim3(512), 0, stream,
                       x, W, bias, gamma, beta, segc_all, segi_all, (float4*)d_out);
}